// Round 2
// baseline (499.996 us; speedup 1.0000x reference)
//
#include <hip/hip_runtime.h>

// Problem constants (n=8, c=64, h=w=256, points=8192)
#define NB    8
#define NC    64
#define HDIM  256
#define HW    65536        // 256*256
#define NPTS  8192
#define TOTPTS (NB*NPTS)   // 65536
#define N1    33554432     // 8*64*256*256 (x_out elements)

__device__ __forceinline__ int reflect_idx(int t) {
    t = t < 0 ? -t : t;
    return t > 255 ? 510 - t : t;
}

// ---------------------------------------------------------------------------
// Build winner map: map[n][ph*256+pw] = p (races between duplicate points are
// benign: duplicates compute identical fusion values).
// ---------------------------------------------------------------------------
__global__ __launch_bounds__(256) void scatter_map_kernel(
    const int* __restrict__ sfl, int* __restrict__ map)
{
    int p  = blockIdx.x * 256 + threadIdx.x;   // 0..65535
    int n  = p >> 13;
    int ph = sfl[2 * p];
    int pw = sfl[2 * p + 1];
    map[(n << 16) + (ph << 8) + pw] = p;
}

// ---------------------------------------------------------------------------
// Fused pass over x2 AND x1 (both NCHW, per-batch 64 x 65536):
//   - transpose x2 tile -> x2t (NHWC)
//   - for x1 tile: rows whose hw position is a winner get written as a
//     coalesced 64-channel xp row into fus[w][0..63] (later overwritten by
//     the attention result in-place).
// Block = 256 threads, tile = 64(hw) x 64(c), LDS padded (65) for banks.
// ---------------------------------------------------------------------------
__global__ __launch_bounds__(256) void transpose_extract_kernel(
    const float* __restrict__ x2, const float* __restrict__ x1,
    const int* __restrict__ map, float* __restrict__ x2t,
    float* __restrict__ fus)
{
    __shared__ float tile[64][65];
    int nb  = blockIdx.x;          // 0..8191  (8 n * 1024 tiles)
    int n   = nb >> 10;
    int hw0 = (nb & 1023) << 6;    // tile base in hw
    int t    = threadIdx.x;
    int lane = t & 63;
    int grp  = t >> 6;             // wave id 0..3

    // ---- x2: load tile (coalesced rows per channel) ----
    const float* src2 = x2 + ((size_t)n << 22);   // n*64*65536
#pragma unroll
    for (int i = 0; i < 16; ++i) {
        int c = (grp << 4) + i;
        tile[lane][c] = src2[((size_t)c << 16) + (size_t)(hw0 + lane)];
    }
    __syncthreads();
    // ---- x2: store transposed (coalesced 256B per row) ----
    float* dst = x2t + (((size_t)n << 16) + (size_t)hw0) * NC;
#pragma unroll
    for (int i = 0; i < 16; ++i) {
        int hw = (grp << 4) + i;
        dst[((size_t)hw << 6) + lane] = tile[hw][lane];
    }
    __syncthreads();

    // ---- x1: load tile ----
    const float* src1 = x1 + ((size_t)n << 22);
#pragma unroll
    for (int i = 0; i < 16; ++i) {
        int c = (grp << 4) + i;
        tile[lane][c] = src1[((size_t)c << 16) + (size_t)(hw0 + lane)];
    }
    __syncthreads();
    // ---- x1: extract winner rows -> fus (coalesced 256B per winner) ----
#pragma unroll
    for (int i = 0; i < 16; ++i) {
        int row = (grp << 4) + i;
        int w = map[(n << 16) + hw0 + row];      // wave-uniform load
        if (w >= 0) fus[((size_t)w << 6) + lane] = tile[row][lane];
    }
}

// ---------------------------------------------------------------------------
// Attention: one wave (64 lanes = 64 channels) per point. All loads coalesced:
// xp from fus[p] (written by extract), xa windows from NHWC x2t. Result
// (x1 + alpha*fusion) overwrites fus[p] in place. Loser duplicates read
// garbage xp -> finite garbage result -> never read by merge.
// ---------------------------------------------------------------------------
__global__ __launch_bounds__(256) void attn_fast_kernel(
    const float* __restrict__ x2t, const int* __restrict__ sfl,
    const float* __restrict__ alpha_p, float* __restrict__ fus)
{
    int p    = (blockIdx.x << 2) + (threadIdx.x >> 6);  // point id, 0..65535
    int lane = threadIdx.x & 63;                         // channel
    int n    = p >> 13;
    int ph   = sfl[2 * p];
    int pw   = sfl[2 * p + 1];
    float alpha = alpha_p[0];

    float xp = fus[((size_t)p << 6) + lane];

    float xa[25];
#pragma unroll
    for (int k = 0; k < 25; ++k) {
        int rh = reflect_idx(ph + k / 5 - 2);
        int rw = reflect_idx(pw + k % 5 - 2);
        size_t idx = ((((size_t)n << 16) + (size_t)((rh << 8) + rw)) << 6) + lane;
        xa[k] = x2t[idx];
    }

    float e[25];
#pragma unroll
    for (int k = 0; k < 25; ++k) {
        float v = xp * xa[k];
        v += __shfl_xor(v, 32);
        v += __shfl_xor(v, 16);
        v += __shfl_xor(v, 8);
        v += __shfl_xor(v, 4);
        v += __shfl_xor(v, 2);
        v += __shfl_xor(v, 1);
        e[k] = v;
    }

    float m = e[0];
#pragma unroll
    for (int k = 1; k < 25; ++k) m = fmaxf(m, e[k]);
    float s = 0.f;
#pragma unroll
    for (int k = 0; k < 25; ++k) { e[k] = __expf(e[k] - m); s += e[k]; }
    float inv = __frcp_rn(s);

    float f = 0.f;
#pragma unroll
    for (int k = 0; k < 25; ++k) f += e[k] * xa[k];
    f *= inv;

    fus[((size_t)p << 6) + lane] = xp + alpha * f;
}

// Fallback attention (tiers B/C): NCHW gather for xp and xa.
template<bool COMPACT>
__global__ __launch_bounds__(256) void attn_fallback_kernel(
    const float* __restrict__ x1, const float* __restrict__ x2,
    const int* __restrict__ sfl, const float* __restrict__ alpha_p,
    float* __restrict__ fusion_buf, int* __restrict__ map,
    float* __restrict__ out)
{
    int p    = (blockIdx.x << 2) + (threadIdx.x >> 6);
    int lane = threadIdx.x & 63;
    int n    = p >> 13;
    int ph   = sfl[2 * p];
    int pw   = sfl[2 * p + 1];
    float alpha = alpha_p[0];

    size_t x1idx = (((size_t)(n * NC + lane)) << 16) + (size_t)((ph << 8) + pw);
    float xp = x1[x1idx];

    float xa[25];
#pragma unroll
    for (int k = 0; k < 25; ++k) {
        int rh = reflect_idx(ph + k / 5 - 2);
        int rw = reflect_idx(pw + k % 5 - 2);
        xa[k] = x2[(((size_t)(n * NC + lane)) << 16) + (size_t)((rh << 8) + rw)];
    }
    float e[25];
#pragma unroll
    for (int k = 0; k < 25; ++k) {
        float v = xp * xa[k];
        v += __shfl_xor(v, 32); v += __shfl_xor(v, 16); v += __shfl_xor(v, 8);
        v += __shfl_xor(v, 4);  v += __shfl_xor(v, 2);  v += __shfl_xor(v, 1);
        e[k] = v;
    }
    float m = e[0];
#pragma unroll
    for (int k = 1; k < 25; ++k) m = fmaxf(m, e[k]);
    float s = 0.f;
#pragma unroll
    for (int k = 0; k < 25; ++k) { e[k] = __expf(e[k] - m); s += e[k]; }
    float inv = __frcp_rn(s);
    float f = 0.f;
#pragma unroll
    for (int k = 0; k < 25; ++k) f += e[k] * xa[k];
    f *= inv;
    float val = xp + alpha * f;

    if (COMPACT) {
        fusion_buf[((size_t)p << 6) + lane] = val;
        if (lane == 0) map[(n << 16) + (ph << 8) + pw] = p;
    } else {
        out[x1idx] = val;
    }
}

// ---------------------------------------------------------------------------
// Merge: out = x1*(1+alpha), overridden at winner positions from fus.
// ---------------------------------------------------------------------------
template<bool HAVE_MAP>
__global__ __launch_bounds__(256) void merge_kernel(
    const float* __restrict__ x1, const float* __restrict__ alpha_p,
    const int* __restrict__ map, const float* __restrict__ fusion_buf,
    float* __restrict__ out)
{
    size_t g = (size_t)blockIdx.x * 256 + threadIdx.x;   // float4 index
    float alpha = alpha_p[0];
    float4 x = ((const float4*)x1)[g];
    float sc = 1.0f + alpha;
    float4 o;
    o.x = x.x * sc; o.y = x.y * sc; o.z = x.z * sc; o.w = x.w * sc;
    if (HAVE_MAP) {
        int hw4 = (int)(g & 16383);
        int c   = (int)((g >> 14) & 63);
        int n   = (int)(g >> 20);
        int4 w4 = ((const int4*)map)[((size_t)n << 14) + hw4];
        if (w4.x >= 0) o.x = fusion_buf[((size_t)w4.x << 6) + c];
        if (w4.y >= 0) o.y = fusion_buf[((size_t)w4.y << 6) + c];
        if (w4.z >= 0) o.z = fusion_buf[((size_t)w4.z << 6) + c];
        if (w4.w >= 0) o.w = fusion_buf[((size_t)w4.w << 6) + c];
    }
    ((float4*)out)[g] = o;
}

__global__ __launch_bounds__(256) void tail_kernel(
    const int* __restrict__ sfl, float* __restrict__ outtail)
{
    int i = blockIdx.x * 256 + threadIdx.x;   // 0..131071
    outtail[i] = (float)sfl[i];
}

extern "C" void kernel_launch(void* const* d_in, const int* in_sizes, int n_in,
                              void* d_out, int out_size, void* d_ws, size_t ws_size,
                              hipStream_t stream)
{
    const float* x1    = (const float*)d_in[0];
    const float* x2    = (const float*)d_in[1];
    const int*   sfl   = (const int*)d_in[2];
    const float* alpha = (const float*)d_in[3];
    float* out = (float*)d_out;

    const size_t X2T_BYTES = (size_t)NB * HW * NC * 4;   // 134,217,728
    const size_t FUS_BYTES = (size_t)TOTPTS * NC * 4;    //  16,777,216
    const size_t MAP_BYTES = (size_t)NB * HW * 4;        //   2,097,152

    if (ws_size >= X2T_BYTES + FUS_BYTES + MAP_BYTES) {
        // Tier A: map -> fused transpose+extract -> attn (all coalesced) -> merge
        float* x2t = (float*)d_ws;
        float* fus = (float*)((char*)d_ws + X2T_BYTES);
        int*   map = (int*)((char*)d_ws + X2T_BYTES + FUS_BYTES);
        hipMemsetAsync(map, 0xFF, MAP_BYTES, stream);
        scatter_map_kernel<<<TOTPTS / 256, 256, 0, stream>>>(sfl, map);
        transpose_extract_kernel<<<8192, 256, 0, stream>>>(x2, x1, map, x2t, fus);
        attn_fast_kernel<<<TOTPTS / 4, 256, 0, stream>>>(x2t, sfl, alpha, fus);
        merge_kernel<true><<<N1 / 4 / 256, 256, 0, stream>>>(x1, alpha, map, fus, out);
        tail_kernel<<<(TOTPTS * 2) / 256, 256, 0, stream>>>(sfl, out + N1);
    } else if (ws_size >= FUS_BYTES + MAP_BYTES) {
        // Tier B: no transpose (slow NCHW gather) + compact fusion + merge
        float* fus = (float*)d_ws;
        int*   map = (int*)((char*)d_ws + FUS_BYTES);
        hipMemsetAsync(map, 0xFF, MAP_BYTES, stream);
        attn_fallback_kernel<true><<<TOTPTS / 4, 256, 0, stream>>>(
            x1, x2, sfl, alpha, fus, map, nullptr);
        merge_kernel<true><<<N1 / 4 / 256, 256, 0, stream>>>(x1, alpha, map, fus, out);
        tail_kernel<<<(TOTPTS * 2) / 256, 256, 0, stream>>>(sfl, out + N1);
    } else {
        // Tier C: no workspace — base pass then direct scatter (dups benign)
        merge_kernel<false><<<N1 / 4 / 256, 256, 0, stream>>>(
            x1, alpha, nullptr, nullptr, out);
        attn_fallback_kernel<false><<<TOTPTS / 4, 256, 0, stream>>>(
            x1, x2, sfl, alpha, nullptr, nullptr, out);
        tail_kernel<<<(TOTPTS * 2) / 256, 256, 0, stream>>>(sfl, out + N1);
    }
}

// Round 3
// 423.770 us; speedup vs baseline: 1.1799x; 1.1799x over previous
//
#include <hip/hip_runtime.h>

// Problem constants (n=8, c=64, h=w=256, points=8192)
#define NB    8
#define NC    64
#define HDIM  256
#define HW    65536        // 256*256
#define NPTS  8192
#define TOTPTS (NB*NPTS)   // 65536
#define N1    33554432     // 8*64*256*256 (x_out elements)

__device__ __forceinline__ int reflect_idx(int t) {
    t = t < 0 ? -t : t;
    return t > 255 ? 510 - t : t;
}

// ---------------------------------------------------------------------------
// Build winner map: map[n][ph*256+pw] = p (duplicate races benign: duplicates
// compute identical fusion values).
// ---------------------------------------------------------------------------
__global__ __launch_bounds__(256) void scatter_map_kernel(
    const int* __restrict__ sfl, int* __restrict__ map)
{
    int p  = blockIdx.x * 256 + threadIdx.x;   // 0..65535
    int n  = p >> 13;
    int ph = sfl[2 * p];
    int pw = sfl[2 * p + 1];
    map[(n << 16) + (ph << 8) + pw] = p;
}

// ---------------------------------------------------------------------------
// Vectorized fused pass over x2 AND x1 (NCHW, per batch 64 x 65536):
//   x2 tile -> NHWC x2t; x1 winner rows -> coalesced fus rows.
// float4 global on BOTH sides; LDS pitch 65 -> 2-way bank aliasing (free).
// Single __syncthreads: both tiles loaded up front (8 float4 in flight).
// ---------------------------------------------------------------------------
__global__ __launch_bounds__(256) void transpose_extract_v2(
    const float* __restrict__ x2, const float* __restrict__ x1,
    const int* __restrict__ map, float* __restrict__ x2t,
    float* __restrict__ fus)
{
    __shared__ float tA[64 * 65];
    __shared__ float tB[64 * 65];
    int nb  = blockIdx.x;          // 0..8191  (8 n * 1024 tiles)
    int n   = nb >> 10;
    int hw0 = (nb & 1023) << 6;    // tile base in hw (64 rows)
    int t   = threadIdx.x;

    // ---- load both tiles: lane covers float4 along hw, c = (t>>4) + 16i ----
    int u  = t & 15;               // hw quad index (hw_local = 4u + r)
    int cb = t >> 4;               // channel base 0..15
    const float* src2 = x2 + ((size_t)n << 22);   // n*64*65536
    const float* src1 = x1 + ((size_t)n << 22);
    float4 va[4], vb[4];
#pragma unroll
    for (int i = 0; i < 4; ++i) {
        int c = cb + 16 * i;
        size_t gidx = ((size_t)c << 16) + (size_t)(hw0 + u * 4);
        va[i] = *(const float4*)(src2 + gidx);
        vb[i] = *(const float4*)(src1 + gidx);
    }
#pragma unroll
    for (int i = 0; i < 4; ++i) {
        int c = cb + 16 * i;
#pragma unroll
        for (int r = 0; r < 4; ++r) {
            tA[(u * 4 + r) * 65 + c] = (&va[i].x)[r];
            tB[(u * 4 + r) * 65 + c] = (&vb[i].x)[r];
        }
    }
    __syncthreads();

    // ---- store transposed: lane covers float4 along c, row = (t>>4) + 16i --
    int uc = t & 15;               // c quad index (c = 4*uc + j)
    int rq = t >> 4;               // row base 0..15
    float4* dst = (float4*)(x2t + (((size_t)n << 16) + (size_t)hw0) * 64);
#pragma unroll
    for (int i = 0; i < 4; ++i) {
        int row = rq + 16 * i;
        float4 w;
#pragma unroll
        for (int j = 0; j < 4; ++j) (&w.x)[j] = tA[row * 65 + uc * 4 + j];
        dst[(size_t)row * 16 + uc] = w;
    }
    // ---- extract winner rows of x1 -> fus (coalesced float4) ----
#pragma unroll
    for (int i = 0; i < 4; ++i) {
        int row = rq + 16 * i;
        int wi = map[(n << 16) + hw0 + row];   // 4 distinct addrs per wave
        if (wi >= 0) {
            float4 g;
#pragma unroll
            for (int j = 0; j < 4; ++j) (&g.x)[j] = tB[row * 65 + uc * 4 + j];
            ((float4*)fus)[(size_t)wi * 16 + uc] = g;
        }
    }
}

// ---------------------------------------------------------------------------
// Attention v2: 4 points per wave, 16 lanes per point, lane holds 4 channels.
// All global accesses are float4 (1KB per wave instruction). Butterfly over
// xor {1,2,4,8} stays within each 16-lane quarter. xa reloaded in the PV pass
// (L1/L2-hot) to keep VGPRs low. Result overwrites fus[p] in place.
// ---------------------------------------------------------------------------
__global__ __launch_bounds__(256) void attn_v2_kernel(
    const float* __restrict__ x2t, const int* __restrict__ sfl,
    const float* __restrict__ alpha_p, float* __restrict__ fus)
{
    int p = blockIdx.x * 16 + (threadIdx.x >> 4);   // point id
    int u = threadIdx.x & 15;                        // channel quad (c=4u..4u+3)
    int n = p >> 13;
    int ph = sfl[2 * p];
    int pw = sfl[2 * p + 1];
    float alpha = alpha_p[0];

    const float4* fv = (const float4*)fus;
    float4 xp = fv[(size_t)p * 16 + u];

    int rh[5], rw[5];
#pragma unroll
    for (int d = 0; d < 5; ++d) {
        rh[d] = reflect_idx(ph + d - 2);
        rw[d] = reflect_idx(pw + d - 2);
    }
    const float4* x2v = (const float4*)x2t;
    size_t nbase = ((size_t)n << 16);

    float e[25];
#pragma unroll
    for (int k = 0; k < 25; ++k) {
        int i = k / 5, j = k % 5;
        size_t idx = (nbase + (size_t)((rh[i] << 8) + rw[j])) * 16 + u;
        float4 a = x2v[idx];
        float v = xp.x * a.x + xp.y * a.y + xp.z * a.z + xp.w * a.w;
        v += __shfl_xor(v, 1);
        v += __shfl_xor(v, 2);
        v += __shfl_xor(v, 4);
        v += __shfl_xor(v, 8);
        e[k] = v;
    }

    float m = e[0];
#pragma unroll
    for (int k = 1; k < 25; ++k) m = fmaxf(m, e[k]);
    float s = 0.f;
#pragma unroll
    for (int k = 0; k < 25; ++k) { e[k] = __expf(e[k] - m); s += e[k]; }
    float inv = __frcp_rn(s);

    float4 f = {0.f, 0.f, 0.f, 0.f};
#pragma unroll
    for (int k = 0; k < 25; ++k) {
        int i = k / 5, j = k % 5;
        size_t idx = (nbase + (size_t)((rh[i] << 8) + rw[j])) * 16 + u;
        float4 a = x2v[idx];
        float w = e[k];
        f.x += w * a.x; f.y += w * a.y; f.z += w * a.z; f.w += w * a.w;
    }
    float4 o;
    o.x = xp.x + alpha * (f.x * inv);
    o.y = xp.y + alpha * (f.y * inv);
    o.z = xp.z + alpha * (f.z * inv);
    o.w = xp.w + alpha * (f.w * inv);
    ((float4*)fus)[(size_t)p * 16 + u] = o;
}

// ---------------------------------------------------------------------------
// Merge v2: grid (hw-tile, c-quad, n). Thread owns 4 hw positions (int4 map
// read once) x 4 channels. Winner override fetched as ONE contiguous float4
// per winner per c-quad.
// ---------------------------------------------------------------------------
__global__ __launch_bounds__(256) void merge_v2_kernel(
    const float* __restrict__ x1, const float* __restrict__ alpha_p,
    const int* __restrict__ map, const float* __restrict__ fus,
    float* __restrict__ out)
{
    int n   = blockIdx.z;
    int c4  = blockIdx.y;                              // 0..15
    int hw4 = blockIdx.x * 256 + threadIdx.x;          // 0..16383
    float alpha = alpha_p[0];
    float sc = 1.0f + alpha;

    int4 w4 = ((const int4*)map)[((size_t)n << 14) + hw4];
    const float4* fv = (const float4*)fus;
    float4 f0 = {0,0,0,0}, f1 = {0,0,0,0}, f2 = {0,0,0,0}, f3 = {0,0,0,0};
    bool b0 = w4.x >= 0, b1 = w4.y >= 0, b2 = w4.z >= 0, b3 = w4.w >= 0;
    if (b0) f0 = fv[(size_t)w4.x * 16 + c4];
    if (b1) f1 = fv[(size_t)w4.y * 16 + c4];
    if (b2) f2 = fv[(size_t)w4.z * 16 + c4];
    if (b3) f3 = fv[(size_t)w4.w * 16 + c4];

    const float4* x1v = (const float4*)x1;
    float4* ov = (float4*)out;
#pragma unroll
    for (int j = 0; j < 4; ++j) {
        int c = c4 * 4 + j;
        size_t idx = ((size_t)(n * NC + c) << 14) + hw4;
        float4 x = x1v[idx];
        float4 o;
        o.x = x.x * sc; o.y = x.y * sc; o.z = x.z * sc; o.w = x.w * sc;
        if (b0) o.x = (&f0.x)[j];
        if (b1) o.y = (&f1.x)[j];
        if (b2) o.z = (&f2.x)[j];
        if (b3) o.w = (&f3.x)[j];
        ov[idx] = o;
    }
}

// Tier C base pass: out = x1*(1+alpha)
__global__ __launch_bounds__(256) void scale_kernel(
    const float* __restrict__ x1, const float* __restrict__ alpha_p,
    float* __restrict__ out)
{
    size_t g = (size_t)blockIdx.x * 256 + threadIdx.x;
    float sc = 1.0f + alpha_p[0];
    float4 x = ((const float4*)x1)[g];
    float4 o = {x.x * sc, x.y * sc, x.z * sc, x.w * sc};
    ((float4*)out)[g] = o;
}

// Fallback attention (tiers B/C): NCHW gather for xp and xa.
template<bool COMPACT>
__global__ __launch_bounds__(256) void attn_fallback_kernel(
    const float* __restrict__ x1, const float* __restrict__ x2,
    const int* __restrict__ sfl, const float* __restrict__ alpha_p,
    float* __restrict__ fusion_buf, int* __restrict__ map,
    float* __restrict__ out)
{
    int p    = (blockIdx.x << 2) + (threadIdx.x >> 6);
    int lane = threadIdx.x & 63;
    int n    = p >> 13;
    int ph   = sfl[2 * p];
    int pw   = sfl[2 * p + 1];
    float alpha = alpha_p[0];

    size_t x1idx = (((size_t)(n * NC + lane)) << 16) + (size_t)((ph << 8) + pw);
    float xp = x1[x1idx];

    float xa[25];
#pragma unroll
    for (int k = 0; k < 25; ++k) {
        int rh = reflect_idx(ph + k / 5 - 2);
        int rw = reflect_idx(pw + k % 5 - 2);
        xa[k] = x2[(((size_t)(n * NC + lane)) << 16) + (size_t)((rh << 8) + rw)];
    }
    float e[25];
#pragma unroll
    for (int k = 0; k < 25; ++k) {
        float v = xp * xa[k];
        v += __shfl_xor(v, 32); v += __shfl_xor(v, 16); v += __shfl_xor(v, 8);
        v += __shfl_xor(v, 4);  v += __shfl_xor(v, 2);  v += __shfl_xor(v, 1);
        e[k] = v;
    }
    float m = e[0];
#pragma unroll
    for (int k = 1; k < 25; ++k) m = fmaxf(m, e[k]);
    float s = 0.f;
#pragma unroll
    for (int k = 0; k < 25; ++k) { e[k] = __expf(e[k] - m); s += e[k]; }
    float inv = __frcp_rn(s);
    float f = 0.f;
#pragma unroll
    for (int k = 0; k < 25; ++k) f += e[k] * xa[k];
    f *= inv;
    float val = xp + alpha * f;

    if (COMPACT) {
        fusion_buf[((size_t)p << 6) + lane] = val;
        if (lane == 0) map[(n << 16) + (ph << 8) + pw] = p;
    } else {
        out[x1idx] = val;
    }
}

__global__ __launch_bounds__(256) void tail_kernel(
    const int* __restrict__ sfl, float* __restrict__ outtail)
{
    int i = blockIdx.x * 256 + threadIdx.x;   // 0..131071
    outtail[i] = (float)sfl[i];
}

extern "C" void kernel_launch(void* const* d_in, const int* in_sizes, int n_in,
                              void* d_out, int out_size, void* d_ws, size_t ws_size,
                              hipStream_t stream)
{
    const float* x1    = (const float*)d_in[0];
    const float* x2    = (const float*)d_in[1];
    const int*   sfl   = (const int*)d_in[2];
    const float* alpha = (const float*)d_in[3];
    float* out = (float*)d_out;

    const size_t X2T_BYTES = (size_t)NB * HW * NC * 4;   // 134,217,728
    const size_t FUS_BYTES = (size_t)TOTPTS * NC * 4;    //  16,777,216
    const size_t MAP_BYTES = (size_t)NB * HW * 4;        //   2,097,152

    if (ws_size >= X2T_BYTES + FUS_BYTES + MAP_BYTES) {
        // Tier A: map -> fused transpose+extract -> attn -> merge (all float4)
        float* x2t = (float*)d_ws;
        float* fus = (float*)((char*)d_ws + X2T_BYTES);
        int*   map = (int*)((char*)d_ws + X2T_BYTES + FUS_BYTES);
        hipMemsetAsync(map, 0xFF, MAP_BYTES, stream);
        scatter_map_kernel<<<TOTPTS / 256, 256, 0, stream>>>(sfl, map);
        transpose_extract_v2<<<8192, 256, 0, stream>>>(x2, x1, map, x2t, fus);
        attn_v2_kernel<<<TOTPTS / 16, 256, 0, stream>>>(x2t, sfl, alpha, fus);
        merge_v2_kernel<<<dim3(64, 16, NB), 256, 0, stream>>>(x1, alpha, map, fus, out);
        tail_kernel<<<(TOTPTS * 2) / 256, 256, 0, stream>>>(sfl, out + N1);
    } else if (ws_size >= FUS_BYTES + MAP_BYTES) {
        // Tier B: no transpose (slow NCHW gather) + compact fusion + merge
        float* fus = (float*)d_ws;
        int*   map = (int*)((char*)d_ws + FUS_BYTES);
        hipMemsetAsync(map, 0xFF, MAP_BYTES, stream);
        attn_fallback_kernel<true><<<TOTPTS / 4, 256, 0, stream>>>(
            x1, x2, sfl, alpha, fus, map, nullptr);
        merge_v2_kernel<<<dim3(64, 16, NB), 256, 0, stream>>>(x1, alpha, map, fus, out);
        tail_kernel<<<(TOTPTS * 2) / 256, 256, 0, stream>>>(sfl, out + N1);
    } else {
        // Tier C: no workspace — base pass then direct scatter (dups benign)
        scale_kernel<<<N1 / 4 / 256, 256, 0, stream>>>(x1, alpha, out);
        attn_fallback_kernel<false><<<TOTPTS / 4, 256, 0, stream>>>(
            x1, x2, sfl, alpha, nullptr, nullptr, out);
        tail_kernel<<<(TOTPTS * 2) / 256, 256, 0, stream>>>(sfl, out + N1);
    }
}